// Round 2
// baseline (194.774 us; speedup 1.0000x reference)
//
#include <hip/hip_runtime.h>
#include <hip/hip_cooperative_groups.h>

namespace cg = cooperative_groups;

#define N_NODES 100000
#define N_EDGES 3200000
#define D 16

#define TILE 128                           // dst nodes per bucket
#define NB ((N_NODES + TILE - 1) / TILE)   // 782 buckets
#define CAP 4608                           // per-bucket ebuf region
#define LT 512                             // threads per block
#define GRID (NB / 2)                      // 391 coop blocks, 2 buckets each
#define SEGR 4096                          // edges per scatter round (2 rounds/block)
#define N4 (N_NODES * D / 4)               // 400000 float4 quarters

// fallback (proven multi-kernel) config
#define NBLK 500
#define SEG (N_EDGES / NBLK)               // 6400
#define BINT 1024
#define CVTB 391

// ---- bf16 helpers (RNE) ----
__device__ __forceinline__ unsigned packbf(float a, float b) {
    unsigned ua = __float_as_uint(a); ua += 0x7FFFu + ((ua >> 16) & 1u);
    unsigned ub = __float_as_uint(b); ub += 0x7FFFu + ((ub >> 16) & 1u);
    return (ua >> 16) | (ub & 0xFFFF0000u);
}
#define BLO(u) __uint_as_float((u) << 16)
#define BHI(u) __uint_as_float((u) & 0xFFFF0000u)

// ---- shared aggregation + transform body (guarded, no early return) ----
#define LDG(j) (*(const uint4*)(xbf + (size_t)(se2[(j) + lane2] & 0x1FFFF) * 8 + ho))
#define ACC8(g) do { \
    acc[0] += BLO((g).x); acc[1] += BHI((g).x); acc[2] += BLO((g).y); acc[3] += BHI((g).y); \
    acc[4] += BLO((g).z); acc[5] += BHI((g).z); acc[6] += BLO((g).w); acc[7] += BHI((g).w); } while (0)

__device__ __forceinline__ void agg_xform(
    const float* __restrict__ xin, const unsigned* __restrict__ xbf,
    const unsigned* se2, const int* lofs, int n_loc,
    const float* sWl, const float* sWc, const float* sbc,
    float* __restrict__ xout, unsigned* __restrict__ xbf_out,
    int emit_bf, int b, int N, int tid) {
    int q = tid & 3;
    int n = b * TILE + n_loc;
    if (n < N) {
        float4 xq = *(const float4*)(xin + (size_t)n * D + q * 4);  // self row (fp32)
        float xv[4] = { xq.x, xq.y, xq.z, xq.w };

        int s0 = lofs[n_loc];
        int s1 = lofs[n_loc + 1];
        int deg = s1 - s0;
        int lane2 = q >> 1;          // edge parity this lane covers
        int ho = (q & 1) * 4;        // uint offset of row half (16B)

        float acc[8] = {0.f,0.f,0.f,0.f,0.f,0.f,0.f,0.f};
        int end8 = s0 + (deg & ~7);
        int i = s0;
        if (i < end8) {
            uint4 c0 = LDG(i + 0), c1 = LDG(i + 2), c2 = LDG(i + 4), c3 = LDG(i + 6);
            i += 8;
            for (; i < end8; i += 8) {
                uint4 n0 = LDG(i + 0), n1 = LDG(i + 2), n2 = LDG(i + 4), n3 = LDG(i + 6);
                ACC8(c0); ACC8(c1); ACC8(c2); ACC8(c3);
                c0 = n0; c1 = n1; c2 = n2; c3 = n3;
            }
            ACC8(c0); ACC8(c1); ACC8(c2); ACC8(c3);
        }
        for (; i + 2 <= s1; i += 2) {
            uint4 g = LDG(i);
            ACC8(g);
        }
        if (i < s1 && lane2 == 0) {          // odd leftover edge: lanes q=0,1 only
            uint4 g = *(const uint4*)(xbf + (size_t)(se2[i] & 0x1FFFF) * 8 + ho);
            ACC8(g);
        }
        #pragma unroll
        for (int k = 0; k < 8; k++) acc[k] += __shfl_xor(acc[k], 2, 4);  // combine parities

        int srcAbs = (tid & 63 & ~3) | (q >> 1);
        float inv = 1.0f / fmaxf((float)deg, 1.0f);
        float a[4];
        #pragma unroll
        for (int k = 0; k < 4; k++) {
            float lo = __shfl(acc[k], srcAbs);
            float hi = __shfl(acc[4 + k], srcAbs);
            a[k] = ((q & 1) ? hi : lo) * inv;
        }

        float o[4];
        #pragma unroll
        for (int j = 0; j < D; j++) {
            float p = 0.f;
            #pragma unroll
            for (int k = 0; k < 4; k++) {
                int kk = q * 4 + k;
                p += a[k] * sWl[j * D + kk] + xv[k] * sWc[j * D + kk];
            }
            p += __shfl_xor(p, 1, 4);
            p += __shfl_xor(p, 2, 4);
            if ((j >> 2) == q) o[j & 3] = p + sbc[j];
        }
        *(float4*)(xout + (size_t)n * D + q * 4) = make_float4(o[0], o[1], o[2], o[3]);
        if (emit_bf) {
            uint2 ob; ob.x = packbf(o[0], o[1]); ob.y = packbf(o[2], o[3]);
            *(uint2*)(xbf_out + (size_t)n * 8 + q * 2) = ob;
        }
    }
}

// ================= fused cooperative kernel (fast path) =================
struct SmemA {                      // 30,864 B
    int lcnt[NB];
    int ldiff[NB];
    unsigned sorted[SEGR];
    unsigned short sbkt[SEGR];
    int wsum[8];
};
struct SmemB {                      // 42,056 B
    unsigned se2[2][CAP];           // sorted edges, both buckets, persist across layers
    int lofs[2][TILE + 1];
    int perm[2][TILE];
    int lc[TILE];                   // transient per bucket
    int sdeg[TILE];                 // transient per bucket
    float sWl[D * D];
    float sWc[D * D];
    float sbc[D];
};
union Smem { SmemA a; SmemB b; };

__global__ __launch_bounds__(LT, 4) void fused_kernel(
        const float* __restrict__ x, const int* __restrict__ src, const int* __restrict__ dst,
        const float* __restrict__ Wl, const float* __restrict__ bl,
        const float* __restrict__ Wr, const float* __restrict__ Wlin,
        const float* __restrict__ blin,
        float* __restrict__ out, unsigned* __restrict__ ebuf,
        float* __restrict__ bufA, float* __restrict__ bufB,
        unsigned* __restrict__ xbf0, unsigned* __restrict__ xbf1,
        int* __restrict__ cursor) {
    __shared__ Smem sm;
    cg::grid_group grid = cg::this_grid();
    int tid = threadIdx.x;
    int b = blockIdx.x;

    // ---- A1: convert x -> bf16 (grid-stride: 391*512 = 200192 threads, 2 iters)
    for (int t = b * LT + tid; t < N4; t += GRID * LT) {
        float4 v = *(const float4*)(x + (size_t)t * 4);
        uint2 o; o.x = packbf(v.x, v.y); o.y = packbf(v.z, v.w);
        *(uint2*)(xbf0 + (size_t)t * 2) = o;
    }

    // ---- A2: bucket-scatter 8192 edges in 2 rounds of 4096
    for (int r = 0; r < 2; ++r) {
        int e0 = b * (2 * SEGR) + r * SEGR;
        int eEnd = min(e0 + SEGR, N_EDGES);
        int nSeg = eEnd - e0;                   // block-uniform, > 0 for all blocks
        __syncthreads();                        // protect LDS reuse across rounds
        for (int i = tid; i < NB; i += LT) sm.a.lcnt[i] = 0;
        __syncthreads();
        for (int e = e0 + tid * 4; e < eEnd; e += LT * 4) {
            int4 d4 = *(const int4*)(dst + e);
            atomicAdd(&sm.a.lcnt[d4.x >> 7], 1);
            atomicAdd(&sm.a.lcnt[d4.y >> 7], 1);
            atomicAdd(&sm.a.lcnt[d4.z >> 7], 1);
            atomicAdd(&sm.a.lcnt[d4.w >> 7], 1);
        }
        __syncthreads();
        // scan NB counters (2/thread), reserve global space
        {
            int lane = tid & 63, wv = tid >> 6;
            int i2 = tid * 2;
            int c0 = (i2 < NB) ? sm.a.lcnt[i2] : 0;
            int c1 = (i2 + 1 < NB) ? sm.a.lcnt[i2 + 1] : 0;
            int v = c0 + c1, s = v;
            #pragma unroll
            for (int d_ = 1; d_ < 64; d_ <<= 1) {
                int u = __shfl_up(s, d_, 64);
                if (lane >= d_) s += u;
            }
            if (lane == 63) sm.a.wsum[wv] = s;
            __syncthreads();
            if (tid == 0) {
                int a_ = 0;
                for (int i = 0; i < 8; i++) { int t_ = sm.a.wsum[i]; sm.a.wsum[i] = a_; a_ += t_; }
            }
            __syncthreads();
            int excl = sm.a.wsum[wv] + s - v;
            if (i2 < NB) {
                int g = c0 ? (i2 * CAP + atomicAdd(&cursor[i2], c0)) : 0;
                sm.a.ldiff[i2] = g - excl;
                sm.a.lcnt[i2] = excl;
            }
            if (i2 + 1 < NB) {
                int e1 = excl + c0;
                int g = c1 ? ((i2 + 1) * CAP + atomicAdd(&cursor[i2 + 1], c1)) : 0;
                sm.a.ldiff[i2 + 1] = g - e1;
                sm.a.lcnt[i2 + 1] = e1;
            }
            __syncthreads();
        }
        // re-read (L2-warm), locally bucket-sort into LDS
        for (int e = e0 + tid * 4; e < eEnd; e += LT * 4) {
            int4 d4 = *(const int4*)(dst + e);
            int4 s4 = *(const int4*)(src + e);
            int b_, pos;
            b_ = d4.x >> 7; pos = atomicAdd(&sm.a.lcnt[b_], 1);
            sm.a.sorted[pos] = ((unsigned)(d4.x & 127) << 17) | (unsigned)s4.x; sm.a.sbkt[pos] = (unsigned short)b_;
            b_ = d4.y >> 7; pos = atomicAdd(&sm.a.lcnt[b_], 1);
            sm.a.sorted[pos] = ((unsigned)(d4.y & 127) << 17) | (unsigned)s4.y; sm.a.sbkt[pos] = (unsigned short)b_;
            b_ = d4.z >> 7; pos = atomicAdd(&sm.a.lcnt[b_], 1);
            sm.a.sorted[pos] = ((unsigned)(d4.z & 127) << 17) | (unsigned)s4.z; sm.a.sbkt[pos] = (unsigned short)b_;
            b_ = d4.w >> 7; pos = atomicAdd(&sm.a.lcnt[b_], 1);
            sm.a.sorted[pos] = ((unsigned)(d4.w & 127) << 17) | (unsigned)s4.w; sm.a.sbkt[pos] = (unsigned short)b_;
        }
        __syncthreads();
        // coalesced write-out
        for (int i = tid; i < nSeg; i += LT)
            ebuf[sm.a.ldiff[sm.a.sbkt[i]] + i] = sm.a.sorted[i];
    }

    __threadfence();
    grid.sync();

    // ---- B: counting-sort both buckets from global ebuf into LDS (once for 3 layers)
    for (int bk = 0; bk < 2; ++bk) {
        int B = 2 * b + bk;
        int base = B * CAP;
        int nE = min(cursor[B], CAP);
        int nE4 = (nE + 3) >> 2;
        __syncthreads();
        if (tid < TILE) sm.b.lc[tid] = 0;
        __syncthreads();
        for (int i4 = tid; i4 < nE4; i4 += LT) {         // count pass (coalesced uint4)
            uint4 qv = ((const uint4*)(ebuf + base))[i4];
            int k0 = i4 * 4;
            if (k0 < nE)     atomicAdd(&sm.b.lc[qv.x >> 17], 1);
            if (k0 + 1 < nE) atomicAdd(&sm.b.lc[qv.y >> 17], 1);
            if (k0 + 2 < nE) atomicAdd(&sm.b.lc[qv.z >> 17], 1);
            if (k0 + 3 < nE) atomicAdd(&sm.b.lc[qv.w >> 17], 1);
        }
        __syncthreads();
        if (tid < 64) {                                  // single-wave scan, 2 counters/lane
            int l2 = tid * 2;
            int c0 = sm.b.lc[l2], c1 = sm.b.lc[l2 + 1];
            int v = c0 + c1, s = v;
            #pragma unroll
            for (int d_ = 1; d_ < 64; d_ <<= 1) {
                int u = __shfl_up(s, d_, 64);
                if (tid >= d_) s += u;
            }
            int excl = s - v;
            sm.b.lofs[bk][l2] = excl; sm.b.sdeg[l2] = c0; sm.b.lc[l2] = excl;
            int e1 = excl + c0;
            sm.b.lofs[bk][l2 + 1] = e1; sm.b.sdeg[l2 + 1] = c1; sm.b.lc[l2 + 1] = e1;
            if (tid == 63) sm.b.lofs[bk][TILE] = s;      // == nE
        }
        __syncthreads();
        if (tid < TILE) {                                // degree rank (desc)
            int dm = sm.b.sdeg[tid];
            int rk = 0;
            for (int j = 0; j < TILE; j++) {
                int dj = sm.b.sdeg[j];
                rk += (dj > dm) || (dj == dm && j < tid);
            }
            sm.b.perm[bk][rk] = tid;
        }
        for (int i4 = tid; i4 < nE4; i4 += LT) {         // place pass (ebuf L2-warm)
            uint4 qv = ((const uint4*)(ebuf + base))[i4];
            int k0 = i4 * 4;
            if (k0 < nE)     { int pos = atomicAdd(&sm.b.lc[qv.x >> 17], 1); sm.b.se2[bk][pos] = qv.x; }
            if (k0 + 1 < nE) { int pos = atomicAdd(&sm.b.lc[qv.y >> 17], 1); sm.b.se2[bk][pos] = qv.y; }
            if (k0 + 2 < nE) { int pos = atomicAdd(&sm.b.lc[qv.z >> 17], 1); sm.b.se2[bk][pos] = qv.z; }
            if (k0 + 3 < nE) { int pos = atomicAdd(&sm.b.lc[qv.w >> 17], 1); sm.b.se2[bk][pos] = qv.w; }
        }
    }
    __syncthreads();

    // ---- 3 layers; edges/lofs/perm persist in LDS; grid.sync between layers
    for (int l = 0; l < 3; ++l) {
        if (l) { __threadfence(); grid.sync(); }
        if (tid < D * D) {
            sm.b.sWl[tid] = Wl[l * D * D + tid];
            sm.b.sWc[tid] = Wr[l * D * D + tid] + Wlin[l * D * D + tid];
        }
        if (tid < D) sm.b.sbc[tid] = bl[l * D + tid] + blin[l * D + tid];
        __syncthreads();
        const float* xin = (l == 0) ? x : (l == 1) ? bufA : bufB;
        float* xout = (l == 0) ? bufA : (l == 1) ? bufB : out;
        const unsigned* xbin = (l == 1) ? xbf1 : xbf0;
        unsigned* xbout = (l == 1) ? xbf0 : xbf1;
        for (int bk = 0; bk < 2; ++bk) {
            int B = 2 * b + bk;
            agg_xform(xin, xbin, sm.b.se2[bk], sm.b.lofs[bk], sm.b.perm[bk][tid >> 2],
                      sm.b.sWl, sm.b.sWc, sm.b.sbc,
                      xout, xbout, (l < 2) ? 1 : 0, B, N_NODES, tid);
        }
    }
}

// ================= fallback: proven multi-kernel pipeline =================
__global__ __launch_bounds__(BINT, 8) void pre_kernel(
        const float* __restrict__ x, unsigned* __restrict__ xbf,
        const int* __restrict__ src, const int* __restrict__ dst,
        int* __restrict__ cursor, unsigned* __restrict__ ebuf) {
    __shared__ int lcnt[NB];
    __shared__ int ldiff[NB];
    __shared__ unsigned sorted[SEG];
    __shared__ unsigned short sbkt[SEG];
    __shared__ int wsum[16];
    int tid = threadIdx.x;

    if (blockIdx.x >= NBLK) {              // ---- cvt path ----
        int t = (blockIdx.x - NBLK) * BINT + tid;
        if (t < N4) {
            float4 v = *(const float4*)(x + (size_t)t * 4);
            uint2 o; o.x = packbf(v.x, v.y); o.y = packbf(v.z, v.w);
            *(uint2*)(xbf + (size_t)t * 2) = o;
        }
        return;
    }

    for (int i = tid; i < NB; i += BINT) lcnt[i] = 0;
    __syncthreads();
    int b0 = blockIdx.x * SEG;
    for (int e = b0 + tid * 4; e < b0 + SEG; e += BINT * 4) {
        int4 d4 = *(const int4*)(dst + e);
        atomicAdd(&lcnt[d4.x >> 7], 1);
        atomicAdd(&lcnt[d4.y >> 7], 1);
        atomicAdd(&lcnt[d4.z >> 7], 1);
        atomicAdd(&lcnt[d4.w >> 7], 1);
    }
    __syncthreads();
    {
        int lane = tid & 63, wv = tid >> 6;
        int v = (tid < NB) ? lcnt[tid] : 0;
        int s = v;
        #pragma unroll
        for (int d_ = 1; d_ < 64; d_ <<= 1) {
            int u = __shfl_up(s, d_, 64);
            if (lane >= d_) s += u;
        }
        if (lane == 63) wsum[wv] = s;
        __syncthreads();
        if (tid == 0) {
            int a = 0;
            #pragma unroll
            for (int i = 0; i < 16; i++) { int t_ = wsum[i]; wsum[i] = a; a += t_; }
        }
        __syncthreads();
        int excl = wsum[wv] + s - v;
        if (tid < NB) {
            int g = v ? (tid * CAP + atomicAdd(&cursor[tid], v)) : 0;
            ldiff[tid] = g - excl;
            lcnt[tid] = excl;
        }
        __syncthreads();
    }
    for (int e = b0 + tid * 4; e < b0 + SEG; e += BINT * 4) {
        int4 d4 = *(const int4*)(dst + e);
        int4 s4 = *(const int4*)(src + e);
        int b_, pos;
        b_ = d4.x >> 7; pos = atomicAdd(&lcnt[b_], 1);
        sorted[pos] = ((unsigned)(d4.x & 127) << 17) | (unsigned)s4.x; sbkt[pos] = (unsigned short)b_;
        b_ = d4.y >> 7; pos = atomicAdd(&lcnt[b_], 1);
        sorted[pos] = ((unsigned)(d4.y & 127) << 17) | (unsigned)s4.y; sbkt[pos] = (unsigned short)b_;
        b_ = d4.z >> 7; pos = atomicAdd(&lcnt[b_], 1);
        sorted[pos] = ((unsigned)(d4.z & 127) << 17) | (unsigned)s4.z; sbkt[pos] = (unsigned short)b_;
        b_ = d4.w >> 7; pos = atomicAdd(&lcnt[b_], 1);
        sorted[pos] = ((unsigned)(d4.w & 127) << 17) | (unsigned)s4.w; sbkt[pos] = (unsigned short)b_;
    }
    __syncthreads();
    for (int i = tid; i < SEG; i += BINT) {
        int b_ = sbkt[i];
        ebuf[ldiff[b_] + i] = sorted[i];
    }
}

__global__ void layer0_kernel(
        const float* __restrict__ xin, const unsigned* __restrict__ xbf,
        unsigned* __restrict__ ebuf, const int* __restrict__ cnt,
        int* __restrict__ node_start, int* __restrict__ gperm,
        const float* __restrict__ Wl, const float* __restrict__ bl,
        const float* __restrict__ Wr, const float* __restrict__ Wlin,
        const float* __restrict__ blin,
        float* __restrict__ xout, unsigned* __restrict__ xbf_out, int N) {
    __shared__ unsigned se[CAP];
    __shared__ unsigned se2[CAP];
    __shared__ int lcnt[TILE];
    __shared__ int lofs[TILE + 1];
    __shared__ int sdeg[TILE];
    __shared__ int perm[TILE];
    __shared__ float sWl[D * D];
    __shared__ float sWc[D * D];
    __shared__ float sbc[D];

    int tid = threadIdx.x;
    int b = blockIdx.x;
    int base = b * CAP;
    int nE = min(cnt[b], CAP);
    int nE4 = (nE + 3) >> 2;

    if (tid < D * D) { sWl[tid] = Wl[tid]; sWc[tid] = Wr[tid] + Wlin[tid]; }
    if (tid < D) sbc[tid] = bl[tid] + blin[tid];
    if (tid < TILE) lcnt[tid] = 0;
    for (int i = tid; i < nE4; i += LT)
        ((uint4*)se)[i] = ((const uint4*)(ebuf + base))[i];
    __syncthreads();
    for (int i = tid; i < nE; i += LT)
        atomicAdd(&lcnt[se[i] >> 17], 1);
    __syncthreads();
    if (tid < 64) {
        int l2 = tid * 2;
        int c0 = lcnt[l2], c1 = lcnt[l2 + 1];
        int v = c0 + c1, s = v;
        #pragma unroll
        for (int d_ = 1; d_ < 64; d_ <<= 1) {
            int u = __shfl_up(s, d_, 64);
            if (tid >= d_) s += u;
        }
        int excl = s - v;
        lofs[l2] = excl; sdeg[l2] = c0; lcnt[l2] = excl;
        node_start[b * TILE + l2] = excl;
        int e1 = excl + c0;
        lofs[l2 + 1] = e1; sdeg[l2 + 1] = c1; lcnt[l2 + 1] = e1;
        node_start[b * TILE + l2 + 1] = e1;
        if (tid == 63) lofs[TILE] = s;
    }
    __syncthreads();
    if (tid < TILE) {
        int dm = sdeg[tid];
        int r = 0;
        for (int j = 0; j < TILE; j++) {
            int dj = sdeg[j];
            r += (dj > dm) || (dj == dm && j < tid);
        }
        perm[r] = tid;
        gperm[b * TILE + r] = tid;
    }
    for (int i = tid; i < nE; i += LT) {
        unsigned p = se[i];
        int pos = atomicAdd(&lcnt[p >> 17], 1);
        se2[pos] = p;
    }
    __syncthreads();
    for (int i = tid; i < nE4; i += LT)
        ((uint4*)(ebuf + base))[i] = ((const uint4*)se2)[i];

    agg_xform(xin, xbf, se2, lofs, perm[tid >> 2], sWl, sWc, sbc,
              xout, xbf_out, 1, b, N, tid);
}

__global__ __launch_bounds__(LT, 8) void layerN_kernel(
        const float* __restrict__ xin, const unsigned* __restrict__ xbf,
        const unsigned* __restrict__ ebuf, const int* __restrict__ cnt,
        const int* __restrict__ node_start, const int* __restrict__ gperm,
        const float* __restrict__ Wl, const float* __restrict__ bl,
        const float* __restrict__ Wr, const float* __restrict__ Wlin,
        const float* __restrict__ blin,
        float* __restrict__ xout, unsigned* __restrict__ xbf_out,
        int emit_bf, int N) {
    __shared__ unsigned se2[CAP];
    __shared__ int lofs[TILE + 1];
    __shared__ float sWl[D * D];
    __shared__ float sWc[D * D];
    __shared__ float sbc[D];

    int tid = threadIdx.x;
    int b = blockIdx.x;
    int base = b * CAP;
    int nE = min(cnt[b], CAP);
    int nE4 = (nE + 3) >> 2;

    if (tid < D * D) { sWl[tid] = Wl[tid]; sWc[tid] = Wr[tid] + Wlin[tid]; }
    if (tid < D) sbc[tid] = bl[tid] + blin[tid];
    if (tid < TILE) lofs[tid] = node_start[b * TILE + tid];
    if (tid == 0) lofs[TILE] = nE;
    for (int i = tid; i < nE4; i += LT)
        ((uint4*)se2)[i] = ((const uint4*)(ebuf + base))[i];
    int n_loc = gperm[b * TILE + (tid >> 2)];
    __syncthreads();

    agg_xform(xin, xbf, se2, lofs, n_loc, sWl, sWc, sbc,
              xout, xbf_out, emit_bf, b, N, tid);
}

extern "C" void kernel_launch(void* const* d_in, const int* in_sizes, int n_in,
                              void* d_out, int out_size, void* d_ws, size_t ws_size,
                              hipStream_t stream) {
    const float* x    = (const float*)d_in[0];
    const int*   ei   = (const int*)d_in[1];   // (2, E): first E = src, next E = dst
    const float* Wl   = (const float*)d_in[2];
    const float* bl   = (const float*)d_in[3];
    const float* Wr   = (const float*)d_in[4];
    const float* Wlin = (const float*)d_in[5];
    const float* blin = (const float*)d_in[6];
    float* out = (float*)d_out;

    const int* src = ei;
    const int* dst = ei + N_EDGES;

    char* w = (char*)d_ws;
    unsigned* ebuf   = (unsigned*)w;  w += (size_t)NB * CAP * 4;      // 14.4 MB
    float* bufA      = (float*)w;     w += (size_t)N_NODES * D * 4;   // 6.4 MB
    float* bufB      = (float*)w;     w += (size_t)N_NODES * D * 4;   // 6.4 MB
    unsigned* xbf0   = (unsigned*)w;  w += (size_t)N_NODES * 8 * 4;   // 3.2 MB
    unsigned* xbf1   = (unsigned*)w;  w += (size_t)N_NODES * 8 * 4;   // 3.2 MB
    int* cursor      = (int*)w;       w += (size_t)NB * 4;
    int* node_start  = (int*)w;       w += (size_t)NB * TILE * 4;
    int* gperm       = (int*)w;       w += (size_t)NB * TILE * 4;

    // capture-safe host-side gate: can the coop grid be co-resident?
    static int coop_ok = -1;
    if (coop_ok < 0) {
        int dev = 0;
        hipGetDevice(&dev);
        int coop_attr = 0, numCU = 0, maxb = 0;
        hipDeviceGetAttribute(&coop_attr, hipDeviceAttributeCooperativeLaunch, dev);
        hipDeviceGetAttribute(&numCU, hipDeviceAttributeMultiprocessorCount, dev);
        hipError_t oe = hipOccupancyMaxActiveBlocksPerMultiprocessor(
            &maxb, (const void*)fused_kernel, LT, 0);
        coop_ok = (coop_attr && oe == hipSuccess && maxb > 0 &&
                   (long)maxb * (long)numCU >= (long)GRID) ? 1 : 0;
    }

    hipMemsetAsync(cursor, 0, (size_t)NB * 4, stream);

    if (coop_ok) {
        void* args[] = { (void*)&x, (void*)&src, (void*)&dst, (void*)&Wl, (void*)&bl,
                         (void*)&Wr, (void*)&Wlin, (void*)&blin, (void*)&out, (void*)&ebuf,
                         (void*)&bufA, (void*)&bufB, (void*)&xbf0, (void*)&xbf1, (void*)&cursor };
        hipError_t le = hipLaunchCooperativeKernel((const void*)fused_kernel,
                                                   dim3(GRID), dim3(LT), args, 0, stream);
        if (le != hipSuccess) coop_ok = 0;      // fall through to proven path
    }
    if (!coop_ok) {
        pre_kernel<<<NBLK + CVTB, BINT, 0, stream>>>(x, xbf0, src, dst, cursor, ebuf);
        layer0_kernel<<<NB, LT, 0, stream>>>(
            x, xbf0, ebuf, cursor, node_start, gperm,
            Wl, bl, Wr, Wlin, blin, bufA, xbf1, N_NODES);
        layerN_kernel<<<NB, LT, 0, stream>>>(
            bufA, xbf1, ebuf, cursor, node_start, gperm,
            Wl + D * D, bl + D, Wr + D * D, Wlin + D * D, blin + D, bufB, xbf0, 1, N_NODES);
        layerN_kernel<<<NB, LT, 0, stream>>>(
            bufB, xbf0, ebuf, cursor, node_start, gperm,
            Wl + 2 * D * D, bl + 2 * D, Wr + 2 * D * D, Wlin + 2 * D * D, blin + 2 * D,
            out, nullptr, 0, N_NODES);
    }
}

// Round 3
// 188.892 us; speedup vs baseline: 1.0311x; 1.0311x over previous
//
#include <hip/hip_runtime.h>

#define N_NODES 100000
#define N_EDGES 3200000
#define D 16

#define TILE 128                           // dst nodes per bucket
#define NB ((N_NODES + TILE - 1) / TILE)   // 782 buckets
#define CAP 4608                           // per-bucket ebuf region (mean 4096, +8 sigma)
#define NBLK 500                           // scatter blocks
#define SEG (N_EDGES / NBLK)               // 6400 edges per scatter block
#define BINT 1024                          // threads for pre kernel
#define CVTB 391                           // cvt blocks: ceil(400000/1024)
#define LT 512                             // threads for layer kernels (= TILE*4)
#define N4 (N_NODES * D / 4)               // 400000 float4 quarters

// ---- bf16 helpers (RNE) ----
__device__ __forceinline__ unsigned packbf(float a, float b) {
    unsigned ua = __float_as_uint(a); ua += 0x7FFFu + ((ua >> 16) & 1u);
    unsigned ub = __float_as_uint(b); ub += 0x7FFFu + ((ub >> 16) & 1u);
    return (ua >> 16) | (ub & 0xFFFF0000u);
}
#define BLO(u) __uint_as_float((u) << 16)
#define BHI(u) __uint_as_float((u) & 0xFFFF0000u)

// ---- fused pre-pass: blocks [0,NBLK) bucket-scatter edges; rest convert x->bf16 ----
// packed entry: (dst & 127) << 17 | src   (src < 2^17)
__global__ __launch_bounds__(BINT, 8) void pre_kernel(
        const float* __restrict__ x, unsigned* __restrict__ xbf,
        const int* __restrict__ src, const int* __restrict__ dst,
        int* __restrict__ cursor, unsigned* __restrict__ ebuf) {
    __shared__ int lcnt[NB];
    __shared__ int ldiff[NB];
    __shared__ unsigned sorted[SEG];
    __shared__ unsigned short sbkt[SEG];
    __shared__ int wsum[16];
    int tid = threadIdx.x;

    if (blockIdx.x >= NBLK) {              // ---- cvt path ----
        int t = (blockIdx.x - NBLK) * BINT + tid;
        if (t < N4) {
            float4 v = *(const float4*)(x + (size_t)t * 4);
            uint2 o; o.x = packbf(v.x, v.y); o.y = packbf(v.z, v.w);
            *(uint2*)(xbf + (size_t)t * 2) = o;
        }
        return;
    }

    // ---- scatter path ----
    for (int i = tid; i < NB; i += BINT) lcnt[i] = 0;
    __syncthreads();
    int b0 = blockIdx.x * SEG;
    for (int e = b0 + tid * 4; e < b0 + SEG; e += BINT * 4) {
        int4 d4 = *(const int4*)(dst + e);
        atomicAdd(&lcnt[d4.x >> 7], 1);
        atomicAdd(&lcnt[d4.y >> 7], 1);
        atomicAdd(&lcnt[d4.z >> 7], 1);
        atomicAdd(&lcnt[d4.w >> 7], 1);
    }
    __syncthreads();
    // wave-shfl scan over NB counters (1/thread), reserve global space
    {
        int lane = tid & 63, wv = tid >> 6;
        int v = (tid < NB) ? lcnt[tid] : 0;
        int s = v;
        #pragma unroll
        for (int d_ = 1; d_ < 64; d_ <<= 1) {
            int u = __shfl_up(s, d_, 64);
            if (lane >= d_) s += u;
        }
        if (lane == 63) wsum[wv] = s;
        __syncthreads();
        if (tid == 0) {
            int a = 0;
            #pragma unroll
            for (int i = 0; i < 16; i++) { int t_ = wsum[i]; wsum[i] = a; a += t_; }
        }
        __syncthreads();
        int excl = wsum[wv] + s - v;
        if (tid < NB) {
            int g = v ? (tid * CAP + atomicAdd(&cursor[tid], v)) : 0;
            ldiff[tid] = g - excl;
            lcnt[tid] = excl;              // running local cursor
        }
        __syncthreads();
    }
    // re-read edges (L2-warm), place into bucket-sorted LDS
    for (int e = b0 + tid * 4; e < b0 + SEG; e += BINT * 4) {
        int4 d4 = *(const int4*)(dst + e);
        int4 s4 = *(const int4*)(src + e);
        int b_, pos;
        b_ = d4.x >> 7; pos = atomicAdd(&lcnt[b_], 1);
        sorted[pos] = ((unsigned)(d4.x & 127) << 17) | (unsigned)s4.x; sbkt[pos] = (unsigned short)b_;
        b_ = d4.y >> 7; pos = atomicAdd(&lcnt[b_], 1);
        sorted[pos] = ((unsigned)(d4.y & 127) << 17) | (unsigned)s4.y; sbkt[pos] = (unsigned short)b_;
        b_ = d4.z >> 7; pos = atomicAdd(&lcnt[b_], 1);
        sorted[pos] = ((unsigned)(d4.z & 127) << 17) | (unsigned)s4.z; sbkt[pos] = (unsigned short)b_;
        b_ = d4.w >> 7; pos = atomicAdd(&lcnt[b_], 1);
        sorted[pos] = ((unsigned)(d4.w & 127) << 17) | (unsigned)s4.w; sbkt[pos] = (unsigned short)b_;
    }
    __syncthreads();
    // coalesced write-out
    for (int i = tid; i < SEG; i += BINT) {
        int b_ = sbkt[i];
        ebuf[ldiff[b_] + i] = sorted[i];
    }
}

// ---- shared aggregation + transform body ----
// 4-lane group per node; 2 lanes/edge, 16B bf16 gathers, SOFTWARE-PIPELINED.
// Serial per-node tail replaced by ONE masked batch (clamped index, 0/1 FMA mask):
// one latency window instead of up to 3-4 dependent ones.
#define LDG(j) (*(const uint4*)(xbf + (size_t)(se2[(j) + lane2] & 0x1FFFF) * 8 + ho))
#define LDC(j) (*(const uint4*)(xbf + (size_t)(se2[min((j) + lane2, s1m1)] & 0x1FFFF) * 8 + ho))
#define ACC8(g) do { \
    acc[0] += BLO((g).x); acc[1] += BHI((g).x); acc[2] += BLO((g).y); acc[3] += BHI((g).y); \
    acc[4] += BLO((g).z); acc[5] += BHI((g).z); acc[6] += BLO((g).w); acc[7] += BHI((g).w); } while (0)
#define ACC8M(g, m) do { \
    acc[0] = fmaf((m), BLO((g).x), acc[0]); acc[1] = fmaf((m), BHI((g).x), acc[1]); \
    acc[2] = fmaf((m), BLO((g).y), acc[2]); acc[3] = fmaf((m), BHI((g).y), acc[3]); \
    acc[4] = fmaf((m), BLO((g).z), acc[4]); acc[5] = fmaf((m), BHI((g).z), acc[5]); \
    acc[6] = fmaf((m), BLO((g).w), acc[6]); acc[7] = fmaf((m), BHI((g).w), acc[7]); } while (0)

__device__ __forceinline__ void agg_xform(
    const float* __restrict__ xin, const unsigned* __restrict__ xbf,
    const unsigned* se2, const int* lofs, int n_loc,
    const float* sWl, const float* sWc, const float* sbc,
    float* __restrict__ xout, unsigned* __restrict__ xbf_out,
    int emit_bf, int b, int N, int tid) {
    int q = tid & 3;
    int n = b * TILE + n_loc;
    if (n >= N) return;

    float4 xq = *(const float4*)(xin + (size_t)n * D + q * 4);  // self row (fp32, issued early)
    float xv[4] = { xq.x, xq.y, xq.z, xq.w };

    int s0 = lofs[n_loc];
    int s1 = lofs[n_loc + 1];
    int deg = s1 - s0;
    int lane2 = q >> 1;          // edge parity this lane covers
    int ho = (q & 1) * 4;        // uint offset of row half (16B)

    float acc[8] = {0.f,0.f,0.f,0.f,0.f,0.f,0.f,0.f};
    int end8 = s0 + (deg & ~7);
    int i = s0;
    if (i < end8) {
        uint4 c0 = LDG(i + 0), c1 = LDG(i + 2), c2 = LDG(i + 4), c3 = LDG(i + 6);
        i += 8;
        for (; i < end8; i += 8) {
            uint4 n0 = LDG(i + 0), n1 = LDG(i + 2), n2 = LDG(i + 4), n3 = LDG(i + 6);
            ACC8(c0); ACC8(c1); ACC8(c2); ACC8(c3);
            c0 = n0; c1 = n1; c2 = n2; c3 = n3;
        }
        ACC8(c0); ACC8(c1); ACC8(c2); ACC8(c3);
    }
    if (i < s1) {                // masked epilogue batch: 4 independent loads, 1 latency window
        int s1m1 = s1 - 1;
        int j0 = i + lane2;
        float m0 = (j0 + 0 < s1) ? 1.f : 0.f;
        float m1 = (j0 + 2 < s1) ? 1.f : 0.f;
        float m2 = (j0 + 4 < s1) ? 1.f : 0.f;
        float m3 = (j0 + 6 < s1) ? 1.f : 0.f;
        uint4 e0 = LDC(i + 0), e1 = LDC(i + 2), e2 = LDC(i + 4), e3 = LDC(i + 6);
        ACC8M(e0, m0); ACC8M(e1, m1); ACC8M(e2, m2); ACC8M(e3, m3);
    }
    #pragma unroll
    for (int k = 0; k < 8; k++) acc[k] += __shfl_xor(acc[k], 2, 4);  // combine parities

    // redistribute half-row sums -> quarter layout: lane q wants f[4q+k]
    int srcAbs = (tid & 63 & ~3) | (q >> 1);
    float inv = 1.0f / fmaxf((float)deg, 1.0f);
    float a[4];
    #pragma unroll
    for (int k = 0; k < 4; k++) {
        float lo = __shfl(acc[k], srcAbs);
        float hi = __shfl(acc[4 + k], srcAbs);
        a[k] = ((q & 1) ? hi : lo) * inv;
    }

    float o[4];
    #pragma unroll
    for (int j = 0; j < D; j++) {
        float p = 0.f;
        #pragma unroll
        for (int k = 0; k < 4; k++) {
            int kk = q * 4 + k;
            p += a[k] * sWl[j * D + kk] + xv[k] * sWc[j * D + kk];
        }
        p += __shfl_xor(p, 1, 4);
        p += __shfl_xor(p, 2, 4);
        if ((j >> 2) == q) o[j & 3] = p + sbc[j];
    }
    *(float4*)(xout + (size_t)n * D + q * 4) = make_float4(o[0], o[1], o[2], o[3]);
    if (emit_bf) {
        uint2 ob; ob.x = packbf(o[0], o[1]); ob.y = packbf(o[2], o[3]);
        *(uint2*)(xbf_out + (size_t)n * 8 + q * 2) = ob;
    }
}

// ---- layer 1: LDS counting sort + degree rank + agg/transform ----
__global__ void layer0_kernel(
        const float* __restrict__ xin, const unsigned* __restrict__ xbf,
        unsigned* __restrict__ ebuf, const int* __restrict__ cnt,
        int* __restrict__ node_start, int* __restrict__ gperm,
        const float* __restrict__ Wl, const float* __restrict__ bl,
        const float* __restrict__ Wr, const float* __restrict__ Wlin,
        const float* __restrict__ blin,
        float* __restrict__ xout, unsigned* __restrict__ xbf_out, int N) {
    __shared__ unsigned se[CAP];
    __shared__ unsigned se2[CAP];
    __shared__ int lcnt[TILE];
    __shared__ int lofs[TILE + 1];
    __shared__ int sdeg[TILE];
    __shared__ int perm[TILE];
    __shared__ float sWl[D * D];
    __shared__ float sWc[D * D];
    __shared__ float sbc[D];

    int tid = threadIdx.x;
    int b = blockIdx.x;
    int base = b * CAP;
    int nE = min(cnt[b], CAP);
    int nE4 = (nE + 3) >> 2;

    if (tid < D * D) { sWl[tid] = Wl[tid]; sWc[tid] = Wr[tid] + Wlin[tid]; }
    if (tid < D) sbc[tid] = bl[tid] + blin[tid];
    if (tid < TILE) lcnt[tid] = 0;
    // uint4 staging of bucket edges
    for (int i = tid; i < nE4; i += LT)
        ((uint4*)se)[i] = ((const uint4*)(ebuf + base))[i];
    __syncthreads();
    for (int i = tid; i < nE; i += LT)
        atomicAdd(&lcnt[se[i] >> 17], 1);
    __syncthreads();
    // single-wave shfl scan over TILE counters (2/lane)
    if (tid < 64) {
        int l2 = tid * 2;
        int c0 = lcnt[l2], c1 = lcnt[l2 + 1];
        int v = c0 + c1, s = v;
        #pragma unroll
        for (int d_ = 1; d_ < 64; d_ <<= 1) {
            int u = __shfl_up(s, d_, 64);
            if (tid >= d_) s += u;
        }
        int excl = s - v;
        lofs[l2] = excl; sdeg[l2] = c0; lcnt[l2] = excl;
        node_start[b * TILE + l2] = excl;
        int e1 = excl + c0;
        lofs[l2 + 1] = e1; sdeg[l2 + 1] = c1; lcnt[l2 + 1] = e1;
        node_start[b * TILE + l2 + 1] = e1;
        if (tid == 63) lofs[TILE] = s;       // == nE
    }
    __syncthreads();
    // degree rank (desc)
    if (tid < TILE) {
        int dm = sdeg[tid];
        int r = 0;
        for (int j = 0; j < TILE; j++) {
            int dj = sdeg[j];
            r += (dj > dm) || (dj == dm && j < tid);
        }
        perm[r] = tid;
        gperm[b * TILE + r] = tid;
    }
    // reorder into sorted se2
    for (int i = tid; i < nE; i += LT) {
        unsigned p = se[i];
        int pos = atomicAdd(&lcnt[p >> 17], 1);
        se2[pos] = p;
    }
    __syncthreads();
    for (int i = tid; i < nE4; i += LT)      // uint4 sorted write-back
        ((uint4*)(ebuf + base))[i] = ((const uint4*)se2)[i];

    agg_xform(xin, xbf, se2, lofs, perm[tid >> 2], sWl, sWc, sbc,
              xout, xbf_out, 1, b, N, tid);
}

// ---- layers 2/3: stage sorted edges, agg/transform ----
__global__ __launch_bounds__(LT, 8) void layerN_kernel(
        const float* __restrict__ xin, const unsigned* __restrict__ xbf,
        const unsigned* __restrict__ ebuf, const int* __restrict__ cnt,
        const int* __restrict__ node_start, const int* __restrict__ gperm,
        const float* __restrict__ Wl, const float* __restrict__ bl,
        const float* __restrict__ Wr, const float* __restrict__ Wlin,
        const float* __restrict__ blin,
        float* __restrict__ xout, unsigned* __restrict__ xbf_out,
        int emit_bf, int N) {
    __shared__ unsigned se2[CAP];
    __shared__ int lofs[TILE + 1];
    __shared__ float sWl[D * D];
    __shared__ float sWc[D * D];
    __shared__ float sbc[D];

    int tid = threadIdx.x;
    int b = blockIdx.x;
    int base = b * CAP;
    int nE = min(cnt[b], CAP);
    int nE4 = (nE + 3) >> 2;

    if (tid < D * D) { sWl[tid] = Wl[tid]; sWc[tid] = Wr[tid] + Wlin[tid]; }
    if (tid < D) sbc[tid] = bl[tid] + blin[tid];
    if (tid < TILE) lofs[tid] = node_start[b * TILE + tid];
    if (tid == 0) lofs[TILE] = nE;
    for (int i = tid; i < nE4; i += LT)      // uint4 staging
        ((uint4*)se2)[i] = ((const uint4*)(ebuf + base))[i];
    int n_loc = gperm[b * TILE + (tid >> 2)];
    __syncthreads();

    agg_xform(xin, xbf, se2, lofs, n_loc, sWl, sWc, sbc,
              xout, xbf_out, emit_bf, b, N, tid);
}

extern "C" void kernel_launch(void* const* d_in, const int* in_sizes, int n_in,
                              void* d_out, int out_size, void* d_ws, size_t ws_size,
                              hipStream_t stream) {
    const float* x    = (const float*)d_in[0];
    const int*   ei   = (const int*)d_in[1];   // (2, E): first E = src, next E = dst
    const float* Wl   = (const float*)d_in[2];
    const float* bl   = (const float*)d_in[3];
    const float* Wr   = (const float*)d_in[4];
    const float* Wlin = (const float*)d_in[5];
    const float* blin = (const float*)d_in[6];
    float* out = (float*)d_out;

    const int* src = ei;
    const int* dst = ei + N_EDGES;

    char* w = (char*)d_ws;
    unsigned* ebuf   = (unsigned*)w;  w += (size_t)NB * CAP * 4;        // 14.4 MB
    float* bufA      = (float*)w;     w += (size_t)N_NODES * D * 4;     // 6.4 MB
    float* bufB      = (float*)w;     w += (size_t)N_NODES * D * 4;     // 6.4 MB
    unsigned* xbf0   = (unsigned*)w;  w += (size_t)N_NODES * 8 * 4;     // 3.2 MB
    unsigned* xbf1   = (unsigned*)w;  w += (size_t)N_NODES * 8 * 4;     // 3.2 MB
    int*   cursor    = (int*)w;       w += (size_t)NB * 4;
    int*   node_start= (int*)w;       w += (size_t)NB * TILE * 4;       // 400 KB
    int*   gperm     = (int*)w;       w += (size_t)NB * TILE * 4;       // 400 KB

    hipMemsetAsync(cursor, 0, (size_t)NB * 4, stream);
    pre_kernel<<<NBLK + CVTB, BINT, 0, stream>>>(x, xbf0, src, dst, cursor, ebuf);

    layer0_kernel<<<NB, LT, 0, stream>>>(
        x, xbf0, ebuf, cursor, node_start, gperm,
        Wl, bl, Wr, Wlin, blin, bufA, xbf1, N_NODES);
    layerN_kernel<<<NB, LT, 0, stream>>>(
        bufA, xbf1, ebuf, cursor, node_start, gperm,
        Wl + D * D, bl + D, Wr + D * D, Wlin + D * D, blin + D, bufB, xbf0, 1, N_NODES);
    layerN_kernel<<<NB, LT, 0, stream>>>(
        bufB, xbf0, ebuf, cursor, node_start, gperm,
        Wl + 2 * D * D, bl + 2 * D, Wr + 2 * D * D, Wlin + 2 * D * D, blin + 2 * D,
        out, nullptr, 0, N_NODES);
}